// Round 11
// baseline (522.793 us; speedup 1.0000x reference)
//
#include <hip/hip_runtime.h>
#include <math.h>

#define TCTX 4096
#define HEADS 16
#define W3 3072
#define BQ 128   // 128 query rows per block (8 waves)
#define BK 64
#define NT 512
#define HSTR 72   // short LDS row stride (144B rows, 16B aligned)

typedef short bf16x8 __attribute__((ext_vector_type(8)));
typedef float f32x4 __attribute__((ext_vector_type(4)));

static __device__ __forceinline__ unsigned short f2bf(float x) {
    union { float f; unsigned int u; } v; v.f = x;
    unsigned int r = v.u + 0x7fffu + ((v.u >> 16) & 1u);  // RNE
    return (unsigned short)(r >> 16);
}
static __device__ __forceinline__ float bf2f(unsigned short h) {
    union { float f; unsigned int u; } v; v.u = ((unsigned int)h) << 16;
    return v.f;
}
#define PK2(a,b) ((unsigned int)(a) | ((unsigned int)(b) << 16))

// R18 = R17 (verified: passed, bitwise 4.88e-4, 510.7us) + re-landed C-layout
// softmax (R13's delta, exonerated: its failure occurred in the 2-blocks/CU
// corruption regime, which R15/R16 proved is the real poison). Deletes Ss
// (33.3KB), barrier D, axs/lin, epilogue broadcast. Row-max is exactly
// associative -> new_m/alpha/p bitwise == R17; only psum order changes
// (~1e-7 rel on l). LDS 144896 -> 110592 B, still >81920 => co-residency
// structurally impossible (safe regime). K/V prefetch + all other phases
// R17-verbatim.
__global__ __launch_bounds__(NT, 1) void attn_r18_kernel(
    const float* __restrict__ qkv,
    const float* __restrict__ q_gamma, const float* __restrict__ q_beta,
    const float* __restrict__ k_gamma, const float* __restrict__ k_beta,
    float* __restrict__ out)
{
    __shared__ unsigned short Qh[BQ * HSTR], Ql[BQ * HSTR];      // 36864 B
    __shared__ unsigned short Kh[BK * HSTR], Kl[BK * HSTR];      // 18432 B
    __shared__ unsigned short Vth[64 * HSTR], Vtl[64 * HSTR];    // 18432 B [ch][key]
    __shared__ unsigned short Ph[BQ * HSTR], Pl[BQ * HSTR];      // 36864 B [row][key]
    // total 110592 B -> exactly 1 block/CU on gfx950 (160 KiB LDS)

    const int tid  = threadIdx.x;
    const int h    = blockIdx.y;
    const int q0   = blockIdx.x * BQ;
    const int lane = tid & 63;
    const int wv   = tid >> 6;          // 0..7
    const int l15  = lane & 15;
    const int quad = lane >> 4;
    const int m0   = wv * 16;           // 0..112
    const int r    = tid >> 2;          // 0..127
    const int j    = tid & 3;

    const float scale = 0.35355339059327373f;  // 64^(-1/4)

    // ---- LayerNorm Q: direct global->reg load (R12 order), rows 0..127 ----
    {
        const float* qp = qkv + (size_t)(q0 + r) * W3 + h * 192 + j * 16;
        f32x4 x0 = *(const f32x4*)(qp);
        f32x4 x1 = *(const f32x4*)(qp + 4);
        f32x4 x2 = *(const f32x4*)(qp + 8);
        f32x4 x3 = *(const f32x4*)(qp + 12);
        float s = 0.f, s2 = 0.f;
        #pragma unroll
        for (int i = 0; i < 16; ++i) {
            float x = (i < 4 ? x0[i & 3] : i < 8 ? x1[i & 3] : i < 12 ? x2[i & 3] : x3[i & 3]);
            s += x; s2 += x * x;
        }
        s  += __shfl_xor(s, 1);  s  += __shfl_xor(s, 2);
        s2 += __shfl_xor(s2, 1); s2 += __shfl_xor(s2, 2);
        float mu   = s * (1.f / 64.f);
        float var  = s2 * (1.f / 64.f) - mu * mu;
        float rsig = rsqrtf(var + 1e-6f);
        unsigned short hi[16], lo[16];
        #pragma unroll
        for (int i = 0; i < 16; ++i) {
            int c = j * 16 + i;
            float x = (i < 4 ? x0[i & 3] : i < 8 ? x1[i & 3] : i < 12 ? x2[i & 3] : x3[i & 3]);
            float y = ((x - mu) * rsig * q_gamma[c] + q_beta[c]) * scale;
            unsigned short yh = f2bf(y);
            hi[i] = yh;
            lo[i] = f2bf(y - bf2f(yh));
        }
        uint4* dh = (uint4*)(Qh + r * HSTR + j * 16);
        dh[0] = make_uint4(PK2(hi[0],hi[1]), PK2(hi[2],hi[3]), PK2(hi[4],hi[5]), PK2(hi[6],hi[7]));
        dh[1] = make_uint4(PK2(hi[8],hi[9]), PK2(hi[10],hi[11]), PK2(hi[12],hi[13]), PK2(hi[14],hi[15]));
        uint4* dl = (uint4*)(Ql + r * HSTR + j * 16);
        dl[0] = make_uint4(PK2(lo[0],lo[1]), PK2(lo[2],lo[3]), PK2(lo[4],lo[5]), PK2(lo[6],lo[7]));
        dl[1] = make_uint4(PK2(lo[8],lo[9]), PK2(lo[10],lo[11]), PK2(lo[12],lo[13]), PK2(lo[14],lo[15]));
    }
    __syncthreads();

    // hoist Q fragments (A[m=lane&15][k=quad*8+j]) — Qh/Ql LDS dead afterwards
    bf16x8 qh0 = *(const bf16x8*)(Qh + (m0 + l15) * HSTR +      quad * 8);
    bf16x8 qh1 = *(const bf16x8*)(Qh + (m0 + l15) * HSTR + 32 + quad * 8);
    bf16x8 ql0 = *(const bf16x8*)(Ql + (m0 + l15) * HSTR +      quad * 8);
    bf16x8 ql1 = *(const bf16x8*)(Ql + (m0 + l15) * HSTR + 32 + quad * 8);

    // softmax state per lane in C-layout: rows m0+quad*4+i
    float mreg[4], lreg[4];
    #pragma unroll
    for (int i = 0; i < 4; ++i) { mreg[i] = -1e30f; lreg[i] = 0.f; }
    f32x4 acco[4];
    #pragma unroll
    for (int t = 0; t < 4; ++t) acco[t] = (f32x4){0.f, 0.f, 0.f, 0.f};

    // ---- prefetch registers for K (waves 0-3) / V (waves 4-7), tile 0 ----
    f32x4 kq0, kq1, kq2, kq3;
    float4 vv0, vv1, vv2, vv3;
    if (tid < 256) {
        const float* kp = qkv + (size_t)(0 + r) * W3 + h * 192 + 64 + j * 16;
        kq0 = *(const f32x4*)(kp);
        kq1 = *(const f32x4*)(kp + 4);
        kq2 = *(const f32x4*)(kp + 8);
        kq3 = *(const f32x4*)(kp + 12);
    } else {
        const int r2 = r - 64;
        const float4* src = (const float4*)(qkv + (size_t)(0 + r2) * W3 + h * 192 + 128 + j * 16);
        vv0 = src[0]; vv1 = src[1]; vv2 = src[2]; vv3 = src[3];
    }

    for (int s0 = 0; s0 < TCTX; s0 += BK) {
        __syncthreads();  // A: prior tile's Kh/Kl/Vth/Vtl/Ph/Pl reads complete

        if (tid < 256) {
            // ---- waves 0-3: LayerNorm K on prefetched regs (R16 math verbatim) ----
            float s = 0.f, s2 = 0.f;
            #pragma unroll
            for (int i = 0; i < 16; ++i) {
                float x = (i < 4 ? kq0[i & 3] : i < 8 ? kq1[i & 3] : i < 12 ? kq2[i & 3] : kq3[i & 3]);
                s += x; s2 += x * x;
            }
            s  += __shfl_xor(s, 1);  s  += __shfl_xor(s, 2);
            s2 += __shfl_xor(s2, 1); s2 += __shfl_xor(s2, 2);
            float mu   = s * (1.f / 64.f);
            float var  = s2 * (1.f / 64.f) - mu * mu;
            float rsig = rsqrtf(var + 1e-6f);
            unsigned short hi[16], lo[16];
            #pragma unroll
            for (int i = 0; i < 16; ++i) {
                int c = j * 16 + i;
                float x = (i < 4 ? kq0[i & 3] : i < 8 ? kq1[i & 3] : i < 12 ? kq2[i & 3] : kq3[i & 3]);
                float y = ((x - mu) * rsig * k_gamma[c] + k_beta[c]) * scale;
                unsigned short yh = f2bf(y);
                hi[i] = yh;
                lo[i] = f2bf(y - bf2f(yh));
            }
            uint4* dh = (uint4*)(Kh + r * HSTR + j * 16);
            dh[0] = make_uint4(PK2(hi[0],hi[1]), PK2(hi[2],hi[3]), PK2(hi[4],hi[5]), PK2(hi[6],hi[7]));
            dh[1] = make_uint4(PK2(hi[8],hi[9]), PK2(hi[10],hi[11]), PK2(hi[12],hi[13]), PK2(hi[14],hi[15]));
            uint4* dl = (uint4*)(Kl + r * HSTR + j * 16);
            dl[0] = make_uint4(PK2(lo[0],lo[1]), PK2(lo[2],lo[3]), PK2(lo[4],lo[5]), PK2(lo[6],lo[7]));
            dl[1] = make_uint4(PK2(lo[8],lo[9]), PK2(lo[10],lo[11]), PK2(lo[12],lo[13]), PK2(lo[14],lo[15]));
        } else {
            // ---- waves 4-7: stage V transposed hi/lo from prefetched regs ----
            const int r2 = r - 64;  // 0..63
            #pragma unroll
            for (int c = 0; c < 4; ++c) {
                float4 v4 = (c == 0 ? vv0 : c == 1 ? vv1 : c == 2 ? vv2 : vv3);
                float vvv[4] = {v4.x, v4.y, v4.z, v4.w};
                #pragma unroll
                for (int k = 0; k < 4; ++k) {
                    unsigned short vh = f2bf(vvv[k]);
                    Vth[(j*16 + 4*c + k) * HSTR + r2] = vh;
                    Vtl[(j*16 + 4*c + k) * HSTR + r2] = f2bf(vvv[k] - bf2f(vh));
                }
            }
        }
        __syncthreads();  // C: Kh/Kl + Vth/Vtl visible

        // ---- S = Q K^T via split MFMA -> accs (C-layout registers, R17 math) ----
        f32x4 accs[4];
        #pragma unroll
        for (int t = 0; t < 4; ++t) accs[t] = (f32x4){0.f, 0.f, 0.f, 0.f};
        #pragma unroll
        for (int s = 0; s < 2; ++s) {
            bf16x8 qh = s ? qh1 : qh0;
            bf16x8 ql = s ? ql1 : ql0;
            #pragma unroll
            for (int t = 0; t < 4; ++t) {
                bf16x8 kh = *(const bf16x8*)(Kh + (t*16 + l15) * HSTR + s*32 + quad*8);
                bf16x8 kl = *(const bf16x8*)(Kl + (t*16 + l15) * HSTR + s*32 + quad*8);
                accs[t] = __builtin_amdgcn_mfma_f32_16x16x32_bf16(ql, kh, accs[t], 0, 0, 0);
                accs[t] = __builtin_amdgcn_mfma_f32_16x16x32_bf16(qh, kl, accs[t], 0, 0, 0);
                accs[t] = __builtin_amdgcn_mfma_f32_16x16x32_bf16(qh, kh, accs[t], 0, 0, 0);
            }
        }

        // ---- softmax in C-layout: row m0+quad*4+i, cols t*16+l15 ----
        // Row lanes = the 16 lanes sharing quad (xor masks 1,2,4,8). Max is
        // exactly associative -> new_m/alpha/p bitwise == R17. Only psum
        // order differs (~1e-7 rel on l).
        float alpha[4];
        #pragma unroll
        for (int i = 0; i < 4; ++i) {
            float mx = fmaxf(fmaxf(accs[0][i], accs[1][i]), fmaxf(accs[2][i], accs[3][i]));
            mx = fmaxf(mx, __shfl_xor(mx, 1));
            mx = fmaxf(mx, __shfl_xor(mx, 2));
            mx = fmaxf(mx, __shfl_xor(mx, 4));
            mx = fmaxf(mx, __shfl_xor(mx, 8));
            float new_m = fmaxf(mreg[i], mx);
            alpha[i] = __expf(mreg[i] - new_m);
            mreg[i]  = new_m;
        }
        float ps[4] = {0.f, 0.f, 0.f, 0.f};
        #pragma unroll
        for (int t = 0; t < 4; ++t) {
            #pragma unroll
            for (int i = 0; i < 4; ++i) {
                float p = __expf(accs[t][i] - mreg[i]);
                ps[i] += p;
                unsigned short ph = f2bf(p);
                const int row = m0 + quad * 4 + i;
                Ph[row * HSTR + t * 16 + l15] = ph;
                Pl[row * HSTR + t * 16 + l15] = f2bf(p - bf2f(ph));
            }
        }
        #pragma unroll
        for (int i = 0; i < 4; ++i) {
            ps[i] += __shfl_xor(ps[i], 1);
            ps[i] += __shfl_xor(ps[i], 2);
            ps[i] += __shfl_xor(ps[i], 4);
            ps[i] += __shfl_xor(ps[i], 8);
            lreg[i] = lreg[i] * alpha[i] + ps[i];
        }
        __syncthreads();  // E: Ph/Pl visible

        // ---- rescale O in-register (alpha owned by the same lanes as acco) ----
        #pragma unroll
        for (int t = 0; t < 4; ++t)
            #pragma unroll
            for (int i = 0; i < 4; ++i)
                acco[t][i] *= alpha[i];

        // ---- issue next tile's K/V global loads (in flight across PV) ----
        if (s0 + BK < TCTX) {
            const int sn = s0 + BK;
            if (tid < 256) {
                const float* kp = qkv + (size_t)(sn + r) * W3 + h * 192 + 64 + j * 16;
                kq0 = *(const f32x4*)(kp);
                kq1 = *(const f32x4*)(kp + 4);
                kq2 = *(const f32x4*)(kp + 8);
                kq3 = *(const f32x4*)(kp + 12);
            } else {
                const int r2 = r - 64;
                const float4* src = (const float4*)(qkv + (size_t)(sn + r2) * W3 + h * 192 + 128 + j * 16);
                vv0 = src[0]; vv1 = src[1]; vv2 = src[2]; vv3 = src[3];
            }
        }

        // ---- O += P V via split MFMA (R17 verbatim) ----
        #pragma unroll
        for (int s = 0; s < 2; ++s) {
            bf16x8 pa_h = *(const bf16x8*)(Ph + (m0 + l15) * HSTR + s*32 + quad*8);
            bf16x8 pa_l = *(const bf16x8*)(Pl + (m0 + l15) * HSTR + s*32 + quad*8);
            #pragma unroll
            for (int t = 0; t < 4; ++t) {
                bf16x8 vb_h = *(const bf16x8*)(Vth + (t*16 + l15) * HSTR + s*32 + quad*8);
                bf16x8 vb_l = *(const bf16x8*)(Vtl + (t*16 + l15) * HSTR + s*32 + quad*8);
                acco[t] = __builtin_amdgcn_mfma_f32_16x16x32_bf16(pa_l, vb_h, acco[t], 0, 0, 0);
                acco[t] = __builtin_amdgcn_mfma_f32_16x16x32_bf16(pa_h, vb_l, acco[t], 0, 0, 0);
                acco[t] = __builtin_amdgcn_mfma_f32_16x16x32_bf16(pa_h, vb_h, acco[t], 0, 0, 0);
            }
        }
    }

    // ---- epilogue: all in-register (lreg owned by the lanes that own acco rows) ----
    #pragma unroll
    for (int i = 0; i < 4; ++i) {
        const float il = 1.f / lreg[i];
        const int row = q0 + m0 + quad * 4 + i;
        float* op = out + (size_t)row * (HEADS * 64) + h * 64 + l15;
        #pragma unroll
        for (int t = 0; t < 4; ++t)
            op[t * 16] = acco[t][i] * il;
    }
}

extern "C" void kernel_launch(void* const* d_in, const int* in_sizes, int n_in,
                              void* d_out, int out_size, void* d_ws, size_t ws_size,
                              hipStream_t stream) {
    const float* qkv     = (const float*)d_in[0];
    const float* q_gamma = (const float*)d_in[1];
    const float* q_beta  = (const float*)d_in[2];
    const float* k_gamma = (const float*)d_in[3];
    const float* k_beta  = (const float*)d_in[4];
    float* out = (float*)d_out;

    dim3 grid(TCTX / BQ, HEADS);
    attn_r18_kernel<<<grid, NT, 0, stream>>>(qkv, q_gamma, q_beta,
                                             k_gamma, k_beta, out);
}

// Round 12
// 500.618 us; speedup vs baseline: 1.0443x; 1.0443x over previous
//
#include <hip/hip_runtime.h>
#include <hip/hip_bf16.h>
#include <math.h>

#define TCTX 4096
#define HEADS 16
#define W3 3072
#define BQ 128   // 128 query rows per block (8 waves)
#define BK 64
#define NT 512
#define LSTR 65   // float LDS row stride (proven layout)
#define HSTR 72   // short LDS row stride (144B rows, 16B aligned)

typedef short bf16x8 __attribute__((ext_vector_type(8)));
typedef float f32x4 __attribute__((ext_vector_type(4)));

// R19 = R17 (verified best: passed, bitwise 4.88e-4, 510.7us) with ONE delta:
// all bf16 hi/lo packing goes through __float22bfloat162_rn (HW
// v_cvt_pk_bf16_f32, RNE) instead of the ~24-integer-op software f2bf path.
// f2bf was RNE -> words bitwise identical; this is pure VALU reduction.
// R18's C-layout softmax REVERTED (it regressed: +2.4%, VALUBusy up).
// (r,j) softmax, Ss scatter, K/V prefetch, MFMA paths all R17-verbatim.
// LDS 144896 B > 81920 => 1 block/CU structural (session co-residency law).

// pack pair (a,b) -> hi word (bf16(a) | bf16(b)<<16) and lo word (residuals)
static __device__ __forceinline__ void packpair(float a, float b,
                                                unsigned int& hw, unsigned int& lw) {
    union { __hip_bfloat162 v; unsigned int u; } H, L;
    H.v = __float22bfloat162_rn(make_float2(a, b));
    float ra = a - __bfloat162float(H.v.x);
    float rb = b - __bfloat162float(H.v.y);
    L.v = __float22bfloat162_rn(make_float2(ra, rb));
    hw = H.u; lw = L.u;
}

__global__ __launch_bounds__(NT, 1) void attn_r19_kernel(
    const float* __restrict__ qkv,
    const float* __restrict__ q_gamma, const float* __restrict__ q_beta,
    const float* __restrict__ k_gamma, const float* __restrict__ k_beta,
    float* __restrict__ out)
{
    __shared__ float Ss[BQ * LSTR];                              // 33280 B
    __shared__ unsigned short Qh[BQ * HSTR], Ql[BQ * HSTR];      // 36864 B
    __shared__ unsigned short Kh[BK * HSTR], Kl[BK * HSTR];      // 18432 B
    __shared__ unsigned short Vth[64 * HSTR], Vtl[64 * HSTR];    // 18432 B [ch][key]
    __shared__ unsigned short Ph[BQ * HSTR], Pl[BQ * HSTR];      // 36864 B [row][key]
    __shared__ float axs[BQ];   // per-row alpha
    __shared__ float lin[BQ];   // per-row 1/l
    // total 144896 B -> exactly 1 block/CU on gfx950 (160 KiB LDS)

    const int tid  = threadIdx.x;
    const int h    = blockIdx.y;
    const int q0   = blockIdx.x * BQ;
    const int lane = tid & 63;
    const int wv   = tid >> 6;          // 0..7
    const int l15  = lane & 15;
    const int quad = lane >> 4;
    const int m0   = wv * 16;           // 0..112
    const int r    = tid >> 2;          // 0..127
    const int j    = tid & 3;

    const float scale = 0.35355339059327373f;  // 64^(-1/4)

    // ---- LayerNorm Q: direct global->reg load (R12 order), rows 0..127 ----
    {
        const float* qp = qkv + (size_t)(q0 + r) * W3 + h * 192 + j * 16;
        f32x4 x0 = *(const f32x4*)(qp);
        f32x4 x1 = *(const f32x4*)(qp + 4);
        f32x4 x2 = *(const f32x4*)(qp + 8);
        f32x4 x3 = *(const f32x4*)(qp + 12);
        float s = 0.f, s2 = 0.f;
        #pragma unroll
        for (int i = 0; i < 16; ++i) {
            float x = (i < 4 ? x0[i & 3] : i < 8 ? x1[i & 3] : i < 12 ? x2[i & 3] : x3[i & 3]);
            s += x; s2 += x * x;
        }
        s  += __shfl_xor(s, 1);  s  += __shfl_xor(s, 2);
        s2 += __shfl_xor(s2, 1); s2 += __shfl_xor(s2, 2);
        float mu   = s * (1.f / 64.f);
        float var  = s2 * (1.f / 64.f) - mu * mu;
        float rsig = rsqrtf(var + 1e-6f);
        float y[16];
        #pragma unroll
        for (int i = 0; i < 16; ++i) {
            int c = j * 16 + i;
            float x = (i < 4 ? x0[i & 3] : i < 8 ? x1[i & 3] : i < 12 ? x2[i & 3] : x3[i & 3]);
            y[i] = ((x - mu) * rsig * q_gamma[c] + q_beta[c]) * scale;
        }
        unsigned int hw[8], lw[8];
        #pragma unroll
        for (int p = 0; p < 8; ++p) packpair(y[2*p], y[2*p+1], hw[p], lw[p]);
        uint4* dh = (uint4*)(Qh + r * HSTR + j * 16);
        dh[0] = make_uint4(hw[0], hw[1], hw[2], hw[3]);
        dh[1] = make_uint4(hw[4], hw[5], hw[6], hw[7]);
        uint4* dl = (uint4*)(Ql + r * HSTR + j * 16);
        dl[0] = make_uint4(lw[0], lw[1], lw[2], lw[3]);
        dl[1] = make_uint4(lw[4], lw[5], lw[6], lw[7]);
    }
    __syncthreads();

    // hoist Q fragments (A[m=lane&15][k=quad*8+j]) — Qh/Ql LDS dead afterwards
    bf16x8 qh0 = *(const bf16x8*)(Qh + (m0 + l15) * HSTR +      quad * 8);
    bf16x8 qh1 = *(const bf16x8*)(Qh + (m0 + l15) * HSTR + 32 + quad * 8);
    bf16x8 ql0 = *(const bf16x8*)(Ql + (m0 + l15) * HSTR +      quad * 8);
    bf16x8 ql1 = *(const bf16x8*)(Ql + (m0 + l15) * HSTR + 32 + quad * 8);

    // softmax state per thread (r,j); O accumulator in MFMA C-layout per lane
    float m = -1e30f;
    float l = 0.f;
    f32x4 acco[4];
    #pragma unroll
    for (int t = 0; t < 4; ++t) acco[t] = (f32x4){0.f, 0.f, 0.f, 0.f};

    // ---- prefetch registers for K (waves 0-3) / V (waves 4-7), tile 0 ----
    f32x4 kq0, kq1, kq2, kq3;
    float4 vv0, vv1, vv2, vv3;
    if (tid < 256) {
        const float* kp = qkv + (size_t)(0 + r) * W3 + h * 192 + 64 + j * 16;
        kq0 = *(const f32x4*)(kp);
        kq1 = *(const f32x4*)(kp + 4);
        kq2 = *(const f32x4*)(kp + 8);
        kq3 = *(const f32x4*)(kp + 12);
    } else {
        const int r2 = r - 64;
        const float4* src = (const float4*)(qkv + (size_t)(0 + r2) * W3 + h * 192 + 128 + j * 16);
        vv0 = src[0]; vv1 = src[1]; vv2 = src[2]; vv3 = src[3];
    }

    for (int s0 = 0; s0 < TCTX; s0 += BK) {
        __syncthreads();  // A: prior tile's Kh/Kl/Vth/Vtl/Ph/Pl/Ss reads complete

        if (tid < 256) {
            // ---- waves 0-3: LayerNorm K on prefetched regs (R17 math order) ----
            float s = 0.f, s2 = 0.f;
            #pragma unroll
            for (int i = 0; i < 16; ++i) {
                float x = (i < 4 ? kq0[i & 3] : i < 8 ? kq1[i & 3] : i < 12 ? kq2[i & 3] : kq3[i & 3]);
                s += x; s2 += x * x;
            }
            s  += __shfl_xor(s, 1);  s  += __shfl_xor(s, 2);
            s2 += __shfl_xor(s2, 1); s2 += __shfl_xor(s2, 2);
            float mu   = s * (1.f / 64.f);
            float var  = s2 * (1.f / 64.f) - mu * mu;
            float rsig = rsqrtf(var + 1e-6f);
            float y[16];
            #pragma unroll
            for (int i = 0; i < 16; ++i) {
                int c = j * 16 + i;
                float x = (i < 4 ? kq0[i & 3] : i < 8 ? kq1[i & 3] : i < 12 ? kq2[i & 3] : kq3[i & 3]);
                y[i] = ((x - mu) * rsig * k_gamma[c] + k_beta[c]) * scale;
            }
            unsigned int hw[8], lw[8];
            #pragma unroll
            for (int p = 0; p < 8; ++p) packpair(y[2*p], y[2*p+1], hw[p], lw[p]);
            uint4* dh = (uint4*)(Kh + r * HSTR + j * 16);
            dh[0] = make_uint4(hw[0], hw[1], hw[2], hw[3]);
            dh[1] = make_uint4(hw[4], hw[5], hw[6], hw[7]);
            uint4* dl = (uint4*)(Kl + r * HSTR + j * 16);
            dl[0] = make_uint4(lw[0], lw[1], lw[2], lw[3]);
            dl[1] = make_uint4(lw[4], lw[5], lw[6], lw[7]);
        } else {
            // ---- waves 4-7: stage V transposed hi/lo from prefetched regs ----
            const int r2 = r - 64;  // 0..63
            #pragma unroll
            for (int c = 0; c < 4; ++c) {
                float4 v4 = (c == 0 ? vv0 : c == 1 ? vv1 : c == 2 ? vv2 : vv3);
                float vvv[4] = {v4.x, v4.y, v4.z, v4.w};
                #pragma unroll
                for (int k = 0; k < 4; k += 2) {
                    unsigned int hw, lw;
                    packpair(vvv[k], vvv[k+1], hw, lw);
                    Vth[(j*16 + 4*c + k)     * HSTR + r2] = (unsigned short)(hw & 0xffffu);
                    Vth[(j*16 + 4*c + k + 1) * HSTR + r2] = (unsigned short)(hw >> 16);
                    Vtl[(j*16 + 4*c + k)     * HSTR + r2] = (unsigned short)(lw & 0xffffu);
                    Vtl[(j*16 + 4*c + k + 1) * HSTR + r2] = (unsigned short)(lw >> 16);
                }
            }
        }
        __syncthreads();  // C: Kh/Kl + Vth/Vtl visible

        // ---- S = Q K^T via split MFMA, scatter C-layout -> Ss fp32 (R17 verbatim) ----
        {
            f32x4 accs[4];
            #pragma unroll
            for (int t = 0; t < 4; ++t) accs[t] = (f32x4){0.f, 0.f, 0.f, 0.f};
            #pragma unroll
            for (int s = 0; s < 2; ++s) {
                bf16x8 qh = s ? qh1 : qh0;
                bf16x8 ql = s ? ql1 : ql0;
                #pragma unroll
                for (int t = 0; t < 4; ++t) {
                    bf16x8 kh = *(const bf16x8*)(Kh + (t*16 + l15) * HSTR + s*32 + quad*8);
                    bf16x8 kl = *(const bf16x8*)(Kl + (t*16 + l15) * HSTR + s*32 + quad*8);
                    accs[t] = __builtin_amdgcn_mfma_f32_16x16x32_bf16(ql, kh, accs[t], 0, 0, 0);
                    accs[t] = __builtin_amdgcn_mfma_f32_16x16x32_bf16(qh, kl, accs[t], 0, 0, 0);
                    accs[t] = __builtin_amdgcn_mfma_f32_16x16x32_bf16(qh, kh, accs[t], 0, 0, 0);
                }
            }
            #pragma unroll
            for (int t = 0; t < 4; ++t)
                #pragma unroll
                for (int i = 0; i < 4; ++i)
                    Ss[(m0 + quad*4 + i) * LSTR + t*16 + l15] = accs[t][i];
        }
        __syncthreads();  // D: Ss visible

        // ---- softmax in (r,j) layout (R17 order; packing via cvt_pk) ----
        {
            float sv[16];
            for (int i = 0; i < 16; ++i)
                sv[i] = Ss[r * LSTR + j * 16 + i];

            float tmax = sv[0];
            for (int i = 1; i < 16; ++i) tmax = fmaxf(tmax, sv[i]);
            tmax = fmaxf(tmax, __shfl_xor(tmax, 1));
            tmax = fmaxf(tmax, __shfl_xor(tmax, 2));
            float new_m = fmaxf(m, tmax);
            float alpha = __expf(m - new_m);
            float psum = 0.f;
            float pv[16];
            for (int i = 0; i < 16; ++i) {
                float p = __expf(sv[i] - new_m);
                psum += p;
                pv[i] = p;
            }
            psum += __shfl_xor(psum, 1);
            psum += __shfl_xor(psum, 2);
            l = l * alpha + psum;
            m = new_m;
            unsigned int hw[8], lw[8];
            #pragma unroll
            for (int p = 0; p < 8; ++p) packpair(pv[2*p], pv[2*p+1], hw[p], lw[p]);
            uint4* dh = (uint4*)(Ph + r * HSTR + j * 16);
            dh[0] = make_uint4(hw[0], hw[1], hw[2], hw[3]);
            dh[1] = make_uint4(hw[4], hw[5], hw[6], hw[7]);
            uint4* dl = (uint4*)(Pl + r * HSTR + j * 16);
            dl[0] = make_uint4(lw[0], lw[1], lw[2], lw[3]);
            dl[1] = make_uint4(lw[4], lw[5], lw[6], lw[7]);
            if (j == 0) axs[r] = alpha;
        }
        __syncthreads();  // E: Ph/Pl + axs visible

        // ---- rescale O (C-layout rows m0+quad*4+i) ----
        {
            float af[4];
            #pragma unroll
            for (int i = 0; i < 4; ++i) af[i] = axs[m0 + quad*4 + i];
            #pragma unroll
            for (int t = 0; t < 4; ++t)
                #pragma unroll
                for (int i = 0; i < 4; ++i)
                    acco[t][i] *= af[i];
        }

        // ---- issue next tile's K/V global loads (in flight across PV) ----
        if (s0 + BK < TCTX) {
            const int sn = s0 + BK;
            if (tid < 256) {
                const float* kp = qkv + (size_t)(sn + r) * W3 + h * 192 + 64 + j * 16;
                kq0 = *(const f32x4*)(kp);
                kq1 = *(const f32x4*)(kp + 4);
                kq2 = *(const f32x4*)(kp + 8);
                kq3 = *(const f32x4*)(kp + 12);
            } else {
                const int r2 = r - 64;
                const float4* src = (const float4*)(qkv + (size_t)(sn + r2) * W3 + h * 192 + 128 + j * 16);
                vv0 = src[0]; vv1 = src[1]; vv2 = src[2]; vv3 = src[3];
            }
        }

        // ---- O += P V via split MFMA (R17 verbatim) ----
        #pragma unroll
        for (int s = 0; s < 2; ++s) {
            bf16x8 pa_h = *(const bf16x8*)(Ph + (m0 + l15) * HSTR + s*32 + quad*8);
            bf16x8 pa_l = *(const bf16x8*)(Pl + (m0 + l15) * HSTR + s*32 + quad*8);
            #pragma unroll
            for (int t = 0; t < 4; ++t) {
                bf16x8 vb_h = *(const bf16x8*)(Vth + (t*16 + l15) * HSTR + s*32 + quad*8);
                bf16x8 vb_l = *(const bf16x8*)(Vtl + (t*16 + l15) * HSTR + s*32 + quad*8);
                acco[t] = __builtin_amdgcn_mfma_f32_16x16x32_bf16(pa_l, vb_h, acco[t], 0, 0, 0);
                acco[t] = __builtin_amdgcn_mfma_f32_16x16x32_bf16(pa_h, vb_l, acco[t], 0, 0, 0);
                acco[t] = __builtin_amdgcn_mfma_f32_16x16x32_bf16(pa_h, vb_h, acco[t], 0, 0, 0);
            }
        }
    }

    // ---- epilogue: 1/l broadcast, normalize, C-layout store (R17 verbatim) ----
    if (j == 0) lin[r] = 1.f / l;
    __syncthreads();
    {
        float il[4];
        #pragma unroll
        for (int i = 0; i < 4; ++i) il[i] = lin[m0 + quad*4 + i];
        #pragma unroll
        for (int i = 0; i < 4; ++i) {
            const int row = q0 + m0 + quad*4 + i;
            float* op = out + (size_t)row * (HEADS * 64) + h * 64 + l15;
            #pragma unroll
            for (int t = 0; t < 4; ++t)
                op[t * 16] = acco[t][i] * il[i];
        }
    }
}

extern "C" void kernel_launch(void* const* d_in, const int* in_sizes, int n_in,
                              void* d_out, int out_size, void* d_ws, size_t ws_size,
                              hipStream_t stream) {
    const float* qkv     = (const float*)d_in[0];
    const float* q_gamma = (const float*)d_in[1];
    const float* q_beta  = (const float*)d_in[2];
    const float* k_gamma = (const float*)d_in[3];
    const float* k_beta  = (const float*)d_in[4];
    float* out = (float*)d_out;

    dim3 grid(TCTX / BQ, HEADS);
    attn_r19_kernel<<<grid, NT, 0, stream>>>(qkv, q_gamma, q_beta,
                                             k_gamma, k_beta, out);
}

// Round 13
// 446.213 us; speedup vs baseline: 1.1716x; 1.1219x over previous
//
#include <hip/hip_runtime.h>
#include <hip/hip_bf16.h>
#include <math.h>

#define TCTX 4096
#define HEADS 16
#define W3 3072
#define BQ 128   // 128 query rows per block (8 waves)
#define BK 64
#define NT 512
#define LSTR 65   // float LDS row stride (proven layout)
#define HSTR 72   // short LDS row stride (144B rows, 16B aligned)

typedef short bf16x8 __attribute__((ext_vector_type(8)));
typedef float f32x4 __attribute__((ext_vector_type(4)));

// R20 = R19 (verified: passed, bitwise 4.88e-4, 500.6us) with ONE delta:
// barriers D and E removed. Proof of safety by wave-ownership:
//   - Ss scatter rows [16wv,16wv+16) are written AND read (softmax r=tid>>2)
//     by the same wave -> wave-private; in-order DS pipe + lgkmcnt suffice.
//   - Ph/Pl rows [16wv,16wv+16) and axs[16wv..16wv+16) are written by wave
//     wv's softmax and read only by wave wv's PV/rescale -> wave-private.
//   - Vth/Vtl reads in PV are covered by barrier C; cross-tile WAR by A.
// Barriers/tile 4 -> 2; waves desync so softmax VALU overlaps PV MFMA across
// waves. Per-thread math untouched -> output bitwise identical to R19.
// LDS 144896 B > 81920 => 1 block/CU structural (session co-residency law).

// pack pair (a,b) -> hi word (bf16(a) | bf16(b)<<16) and lo word (residuals)
static __device__ __forceinline__ void packpair(float a, float b,
                                                unsigned int& hw, unsigned int& lw) {
    union { __hip_bfloat162 v; unsigned int u; } H, L;
    H.v = __float22bfloat162_rn(make_float2(a, b));
    float ra = a - __bfloat162float(H.v.x);
    float rb = b - __bfloat162float(H.v.y);
    L.v = __float22bfloat162_rn(make_float2(ra, rb));
    hw = H.u; lw = L.u;
}

__global__ __launch_bounds__(NT, 1) void attn_r20_kernel(
    const float* __restrict__ qkv,
    const float* __restrict__ q_gamma, const float* __restrict__ q_beta,
    const float* __restrict__ k_gamma, const float* __restrict__ k_beta,
    float* __restrict__ out)
{
    __shared__ float Ss[BQ * LSTR];                              // 33280 B
    __shared__ unsigned short Qh[BQ * HSTR], Ql[BQ * HSTR];      // 36864 B
    __shared__ unsigned short Kh[BK * HSTR], Kl[BK * HSTR];      // 18432 B
    __shared__ unsigned short Vth[64 * HSTR], Vtl[64 * HSTR];    // 18432 B [ch][key]
    __shared__ unsigned short Ph[BQ * HSTR], Pl[BQ * HSTR];      // 36864 B [row][key]
    __shared__ float axs[BQ];   // per-row alpha
    __shared__ float lin[BQ];   // per-row 1/l
    // total 144896 B -> exactly 1 block/CU on gfx950 (160 KiB LDS)

    const int tid  = threadIdx.x;
    const int h    = blockIdx.y;
    const int q0   = blockIdx.x * BQ;
    const int lane = tid & 63;
    const int wv   = tid >> 6;          // 0..7
    const int l15  = lane & 15;
    const int quad = lane >> 4;
    const int m0   = wv * 16;           // 0..112
    const int r    = tid >> 2;          // 0..127
    const int j    = tid & 3;

    const float scale = 0.35355339059327373f;  // 64^(-1/4)

    // ---- LayerNorm Q: direct global->reg load (R12 order), rows 0..127 ----
    {
        const float* qp = qkv + (size_t)(q0 + r) * W3 + h * 192 + j * 16;
        f32x4 x0 = *(const f32x4*)(qp);
        f32x4 x1 = *(const f32x4*)(qp + 4);
        f32x4 x2 = *(const f32x4*)(qp + 8);
        f32x4 x3 = *(const f32x4*)(qp + 12);
        float s = 0.f, s2 = 0.f;
        #pragma unroll
        for (int i = 0; i < 16; ++i) {
            float x = (i < 4 ? x0[i & 3] : i < 8 ? x1[i & 3] : i < 12 ? x2[i & 3] : x3[i & 3]);
            s += x; s2 += x * x;
        }
        s  += __shfl_xor(s, 1);  s  += __shfl_xor(s, 2);
        s2 += __shfl_xor(s2, 1); s2 += __shfl_xor(s2, 2);
        float mu   = s * (1.f / 64.f);
        float var  = s2 * (1.f / 64.f) - mu * mu;
        float rsig = rsqrtf(var + 1e-6f);
        float y[16];
        #pragma unroll
        for (int i = 0; i < 16; ++i) {
            int c = j * 16 + i;
            float x = (i < 4 ? x0[i & 3] : i < 8 ? x1[i & 3] : i < 12 ? x2[i & 3] : x3[i & 3]);
            y[i] = ((x - mu) * rsig * q_gamma[c] + q_beta[c]) * scale;
        }
        unsigned int hw[8], lw[8];
        #pragma unroll
        for (int p = 0; p < 8; ++p) packpair(y[2*p], y[2*p+1], hw[p], lw[p]);
        uint4* dh = (uint4*)(Qh + r * HSTR + j * 16);
        dh[0] = make_uint4(hw[0], hw[1], hw[2], hw[3]);
        dh[1] = make_uint4(hw[4], hw[5], hw[6], hw[7]);
        uint4* dl = (uint4*)(Ql + r * HSTR + j * 16);
        dl[0] = make_uint4(lw[0], lw[1], lw[2], lw[3]);
        dl[1] = make_uint4(lw[4], lw[5], lw[6], lw[7]);
    }
    __syncthreads();

    // hoist Q fragments (A[m=lane&15][k=quad*8+j]) — Qh/Ql LDS dead afterwards
    bf16x8 qh0 = *(const bf16x8*)(Qh + (m0 + l15) * HSTR +      quad * 8);
    bf16x8 qh1 = *(const bf16x8*)(Qh + (m0 + l15) * HSTR + 32 + quad * 8);
    bf16x8 ql0 = *(const bf16x8*)(Ql + (m0 + l15) * HSTR +      quad * 8);
    bf16x8 ql1 = *(const bf16x8*)(Ql + (m0 + l15) * HSTR + 32 + quad * 8);

    // softmax state per thread (r,j); O accumulator in MFMA C-layout per lane
    float m = -1e30f;
    float l = 0.f;
    f32x4 acco[4];
    #pragma unroll
    for (int t = 0; t < 4; ++t) acco[t] = (f32x4){0.f, 0.f, 0.f, 0.f};

    // ---- prefetch registers for K (waves 0-3) / V (waves 4-7), tile 0 ----
    f32x4 kq0, kq1, kq2, kq3;
    float4 vv0, vv1, vv2, vv3;
    if (tid < 256) {
        const float* kp = qkv + (size_t)(0 + r) * W3 + h * 192 + 64 + j * 16;
        kq0 = *(const f32x4*)(kp);
        kq1 = *(const f32x4*)(kp + 4);
        kq2 = *(const f32x4*)(kp + 8);
        kq3 = *(const f32x4*)(kp + 12);
    } else {
        const int r2 = r - 64;
        const float4* src = (const float4*)(qkv + (size_t)(0 + r2) * W3 + h * 192 + 128 + j * 16);
        vv0 = src[0]; vv1 = src[1]; vv2 = src[2]; vv3 = src[3];
    }

    for (int s0 = 0; s0 < TCTX; s0 += BK) {
        __syncthreads();  // A: prior tile's Kh/Kl/Vth/Vtl reads (QK^T/PV) complete

        if (tid < 256) {
            // ---- waves 0-3: LayerNorm K on prefetched regs (R17 math order) ----
            float s = 0.f, s2 = 0.f;
            #pragma unroll
            for (int i = 0; i < 16; ++i) {
                float x = (i < 4 ? kq0[i & 3] : i < 8 ? kq1[i & 3] : i < 12 ? kq2[i & 3] : kq3[i & 3]);
                s += x; s2 += x * x;
            }
            s  += __shfl_xor(s, 1);  s  += __shfl_xor(s, 2);
            s2 += __shfl_xor(s2, 1); s2 += __shfl_xor(s2, 2);
            float mu   = s * (1.f / 64.f);
            float var  = s2 * (1.f / 64.f) - mu * mu;
            float rsig = rsqrtf(var + 1e-6f);
            float y[16];
            #pragma unroll
            for (int i = 0; i < 16; ++i) {
                int c = j * 16 + i;
                float x = (i < 4 ? kq0[i & 3] : i < 8 ? kq1[i & 3] : i < 12 ? kq2[i & 3] : kq3[i & 3]);
                y[i] = ((x - mu) * rsig * k_gamma[c] + k_beta[c]) * scale;
            }
            unsigned int hw[8], lw[8];
            #pragma unroll
            for (int p = 0; p < 8; ++p) packpair(y[2*p], y[2*p+1], hw[p], lw[p]);
            uint4* dh = (uint4*)(Kh + r * HSTR + j * 16);
            dh[0] = make_uint4(hw[0], hw[1], hw[2], hw[3]);
            dh[1] = make_uint4(hw[4], hw[5], hw[6], hw[7]);
            uint4* dl = (uint4*)(Kl + r * HSTR + j * 16);
            dl[0] = make_uint4(lw[0], lw[1], lw[2], lw[3]);
            dl[1] = make_uint4(lw[4], lw[5], lw[6], lw[7]);
        } else {
            // ---- waves 4-7: stage V transposed hi/lo from prefetched regs ----
            const int r2 = r - 64;  // 0..63
            #pragma unroll
            for (int c = 0; c < 4; ++c) {
                float4 v4 = (c == 0 ? vv0 : c == 1 ? vv1 : c == 2 ? vv2 : vv3);
                float vvv[4] = {v4.x, v4.y, v4.z, v4.w};
                #pragma unroll
                for (int k = 0; k < 4; k += 2) {
                    unsigned int hw, lw;
                    packpair(vvv[k], vvv[k+1], hw, lw);
                    Vth[(j*16 + 4*c + k)     * HSTR + r2] = (unsigned short)(hw & 0xffffu);
                    Vth[(j*16 + 4*c + k + 1) * HSTR + r2] = (unsigned short)(hw >> 16);
                    Vtl[(j*16 + 4*c + k)     * HSTR + r2] = (unsigned short)(lw & 0xffffu);
                    Vtl[(j*16 + 4*c + k + 1) * HSTR + r2] = (unsigned short)(lw >> 16);
                }
            }
        }
        __syncthreads();  // C: Kh/Kl + Vth/Vtl visible to all waves

        // ---- S = Q K^T via split MFMA, scatter C-layout -> Ss fp32 ----
        // Scatter rows [16wv,16wv+16) are WAVE-PRIVATE (read back by own
        // wave's softmax below) -> no barrier needed after this.
        {
            f32x4 accs[4];
            #pragma unroll
            for (int t = 0; t < 4; ++t) accs[t] = (f32x4){0.f, 0.f, 0.f, 0.f};
            #pragma unroll
            for (int s = 0; s < 2; ++s) {
                bf16x8 qh = s ? qh1 : qh0;
                bf16x8 ql = s ? ql1 : ql0;
                #pragma unroll
                for (int t = 0; t < 4; ++t) {
                    bf16x8 kh = *(const bf16x8*)(Kh + (t*16 + l15) * HSTR + s*32 + quad*8);
                    bf16x8 kl = *(const bf16x8*)(Kl + (t*16 + l15) * HSTR + s*32 + quad*8);
                    accs[t] = __builtin_amdgcn_mfma_f32_16x16x32_bf16(ql, kh, accs[t], 0, 0, 0);
                    accs[t] = __builtin_amdgcn_mfma_f32_16x16x32_bf16(qh, kl, accs[t], 0, 0, 0);
                    accs[t] = __builtin_amdgcn_mfma_f32_16x16x32_bf16(qh, kh, accs[t], 0, 0, 0);
                }
            }
            #pragma unroll
            for (int t = 0; t < 4; ++t)
                #pragma unroll
                for (int i = 0; i < 4; ++i)
                    Ss[(m0 + quad*4 + i) * LSTR + t*16 + l15] = accs[t][i];
        }
        // (barrier D removed: Ss row-block wave-private, DS pipe in-order)

        // ---- softmax in (r,j) layout (R17 order; packing via cvt_pk) ----
        {
            float sv[16];
            for (int i = 0; i < 16; ++i)
                sv[i] = Ss[r * LSTR + j * 16 + i];

            float tmax = sv[0];
            for (int i = 1; i < 16; ++i) tmax = fmaxf(tmax, sv[i]);
            tmax = fmaxf(tmax, __shfl_xor(tmax, 1));
            tmax = fmaxf(tmax, __shfl_xor(tmax, 2));
            float new_m = fmaxf(m, tmax);
            float alpha = __expf(m - new_m);
            float psum = 0.f;
            float pv[16];
            for (int i = 0; i < 16; ++i) {
                float p = __expf(sv[i] - new_m);
                psum += p;
                pv[i] = p;
            }
            psum += __shfl_xor(psum, 1);
            psum += __shfl_xor(psum, 2);
            l = l * alpha + psum;
            m = new_m;
            unsigned int hw[8], lw[8];
            #pragma unroll
            for (int p = 0; p < 8; ++p) packpair(pv[2*p], pv[2*p+1], hw[p], lw[p]);
            uint4* dh = (uint4*)(Ph + r * HSTR + j * 16);
            dh[0] = make_uint4(hw[0], hw[1], hw[2], hw[3]);
            dh[1] = make_uint4(hw[4], hw[5], hw[6], hw[7]);
            uint4* dl = (uint4*)(Pl + r * HSTR + j * 16);
            dl[0] = make_uint4(lw[0], lw[1], lw[2], lw[3]);
            dl[1] = make_uint4(lw[4], lw[5], lw[6], lw[7]);
            if (j == 0) axs[r] = alpha;
        }
        // (barrier E removed: Ph/Pl rows + axs entries wave-private to wv)

        // ---- rescale O (C-layout rows m0+quad*4+i; axs own-wave) ----
        {
            float af[4];
            #pragma unroll
            for (int i = 0; i < 4; ++i) af[i] = axs[m0 + quad*4 + i];
            #pragma unroll
            for (int t = 0; t < 4; ++t)
                #pragma unroll
                for (int i = 0; i < 4; ++i)
                    acco[t][i] *= af[i];
        }

        // ---- issue next tile's K/V global loads (in flight across PV) ----
        if (s0 + BK < TCTX) {
            const int sn = s0 + BK;
            if (tid < 256) {
                const float* kp = qkv + (size_t)(sn + r) * W3 + h * 192 + 64 + j * 16;
                kq0 = *(const f32x4*)(kp);
                kq1 = *(const f32x4*)(kp + 4);
                kq2 = *(const f32x4*)(kp + 8);
                kq3 = *(const f32x4*)(kp + 12);
            } else {
                const int r2 = r - 64;
                const float4* src = (const float4*)(qkv + (size_t)(sn + r2) * W3 + h * 192 + 128 + j * 16);
                vv0 = src[0]; vv1 = src[1]; vv2 = src[2]; vv3 = src[3];
            }
        }

        // ---- O += P V via split MFMA (A-rows own-wave; V covered by C) ----
        #pragma unroll
        for (int s = 0; s < 2; ++s) {
            bf16x8 pa_h = *(const bf16x8*)(Ph + (m0 + l15) * HSTR + s*32 + quad*8);
            bf16x8 pa_l = *(const bf16x8*)(Pl + (m0 + l15) * HSTR + s*32 + quad*8);
            #pragma unroll
            for (int t = 0; t < 4; ++t) {
                bf16x8 vb_h = *(const bf16x8*)(Vth + (t*16 + l15) * HSTR + s*32 + quad*8);
                bf16x8 vb_l = *(const bf16x8*)(Vtl + (t*16 + l15) * HSTR + s*32 + quad*8);
                acco[t] = __builtin_amdgcn_mfma_f32_16x16x32_bf16(pa_l, vb_h, acco[t], 0, 0, 0);
                acco[t] = __builtin_amdgcn_mfma_f32_16x16x32_bf16(pa_h, vb_l, acco[t], 0, 0, 0);
                acco[t] = __builtin_amdgcn_mfma_f32_16x16x32_bf16(pa_h, vb_h, acco[t], 0, 0, 0);
            }
        }
    }

    // ---- epilogue: 1/l broadcast, normalize, C-layout store (R17 verbatim) ----
    if (j == 0) lin[r] = 1.f / l;
    __syncthreads();
    {
        float il[4];
        #pragma unroll
        for (int i = 0; i < 4; ++i) il[i] = lin[m0 + quad*4 + i];
        #pragma unroll
        for (int i = 0; i < 4; ++i) {
            const int row = q0 + m0 + quad*4 + i;
            float* op = out + (size_t)row * (HEADS * 64) + h * 64 + l15;
            #pragma unroll
            for (int t = 0; t < 4; ++t)
                op[t * 16] = acco[t][i] * il[i];
        }
    }
}

extern "C" void kernel_launch(void* const* d_in, const int* in_sizes, int n_in,
                              void* d_out, int out_size, void* d_ws, size_t ws_size,
                              hipStream_t stream) {
    const float* qkv     = (const float*)d_in[0];
    const float* q_gamma = (const float*)d_in[1];
    const float* q_beta  = (const float*)d_in[2];
    const float* k_gamma = (const float*)d_in[3];
    const float* k_beta  = (const float*)d_in[4];
    float* out = (float*)d_out;

    dim3 grid(TCTX / BQ, HEADS);
    attn_r20_kernel<<<grid, NT, 0, stream>>>(qkv, q_gamma, q_beta,
                                             k_gamma, k_beta, out);
}